// Round 7
// baseline (624.508 us; speedup 1.0000x reference)
//
#include <hip/hip_runtime.h>
#include <hip/hip_fp16.h>

#define LQ      8192
#define LEN_IN_ 126360

typedef _Float16 f16;
typedef f16 f16x2 __attribute__((ext_vector_type(2)));
typedef f16 f16x4 __attribute__((ext_vector_type(4)));
typedef f16 f16x8 __attribute__((ext_vector_type(8)));
typedef float f32x4 __attribute__((ext_vector_type(4)));

__device__ __forceinline__ void gl_lds16(const void* g, void* l) {
  __builtin_amdgcn_global_load_lds(
      (const __attribute__((address_space(1))) unsigned int*)g,
      (__attribute__((address_space(3))) unsigned int*)l, 16, 0, 0);
}

// ---------------- K0: merged prep ----------------
__global__ __launch_bounds__(256) void k0_prep(
    const float* __restrict__ q, f16* __restrict__ q16,
    const float* __restrict__ Woff, const float* __restrict__ Wqkv,
    f16* __restrict__ Bw,
    const float* __restrict__ WO, f16* __restrict__ Mw) {
  const int blk = blockIdx.x;
  const int tid = threadIdx.x;
  if (blk < 4096) {
    const int idx = (blk * 256 + tid) * 4;
    float4 v = *(const float4*)(q + idx);
    f16x4 o = {(f16)v.x, (f16)v.y, (f16)v.z, (f16)v.w};
    *(f16x4*)(q16 + idx) = o;
  } else if (blk < 6528) {
    const int r = blk - 4096, j = tid;
    float v;
    if (r < 384) {
      v = Woff[(size_t)r * 256 + j];
    } else {
      const int e = r - 384, h = e >> 8, d = e & 255;
      float s = 0.f;
#pragma unroll
      for (int c = 0; c < 32; ++c)
        s += Wqkv[(size_t)(h * 32 + c) * 256 + j] *
             Wqkv[(size_t)(256 + h * 32 + c) * 256 + d];
      v = s;
    }
    Bw[(size_t)r * 256 + j] = (f16)v;
  } else {
    const int bid = blk - 6528, d = tid;
    const int o = bid >> 3, h = bid & 7;
    float s = 0.f;
#pragma unroll
    for (int j = 0; j < 32; ++j)
      s += WO[(size_t)o * 256 + h * 32 + j] *
           Wqkv[(size_t)(512 + h * 32 + j) * 256 + d];
    Mw[(size_t)o * 2048 + h * 256 + d] = (f16)s;
  }
}

// ---------------- gemm128: C(M x N) = A(MxK) @ B(NxK)^T, fp16 MFMA ----------------
// 2-phase double-buffered pipeline (T3 minimal): STAGE(next) issued before
// ds_read+MFMA(cur); one vmcnt-drain barrier per K-step.
template <int KSTEPS, int EP>
__global__ __launch_bounds__(256) void gemm128(
    const f16* __restrict__ A, int lda,
    const f16* __restrict__ B, int ldb,
    int nbn,
    const float* __restrict__ bias,
    float* __restrict__ out0,
    __half* __restrict__ out1) {
  __shared__ f16 As[2][128 * 32];
  __shared__ f16 Bs[2][128 * 32];
  const int tid = threadIdx.x;
  const int w = tid >> 6, L = tid & 63;
  const int bn = blockIdx.x % nbn, bm = blockIdx.x / nbn;
  const int i_base = bm * 128;
  const int wr = w >> 1, wc = w & 1;
  const int lr = L & 15, lk = L >> 4;

  f32x4 acc[4][4];
#pragma unroll
  for (int m = 0; m < 4; ++m)
#pragma unroll
    for (int n = 0; n < 4; ++n) acc[m][n] = (f32x4){0.f, 0.f, 0.f, 0.f};

  const int p0 = w * 64 + L;
  // precompute staging addresses (two 256-thread passes cover 128 rows x 32 cols)
  const int pA = p0, pB = 256 + p0;
  const int rA = pA >> 2, cA = (pA & 3) ^ (rA & 3);
  const int rB = pB >> 2, cB = (pB & 3) ^ (rB & 3);
  const f16* gA0 = A + (size_t)(i_base + rA) * lda + cA * 8;
  const f16* gA1 = A + (size_t)(i_base + rB) * lda + cB * 8;
  const f16* gB0 = B + (size_t)(bn * 128 + rA) * ldb + cA * 8;
  const f16* gB1 = B + (size_t)(bn * 128 + rB) * ldb + cB * 8;

#define STAGE(buf, kb)                                                   \
  {                                                                      \
    gl_lds16(gA0 + (kb) * 32, (char*)As[buf] + 0 * 4096 + w * 1024);     \
    gl_lds16(gB0 + (kb) * 32, (char*)Bs[buf] + 0 * 4096 + w * 1024);     \
    gl_lds16(gA1 + (kb) * 32, (char*)As[buf] + 1 * 4096 + w * 1024);     \
    gl_lds16(gB1 + (kb) * 32, (char*)Bs[buf] + 1 * 4096 + w * 1024);     \
  }

  STAGE(0, 0)
  __syncthreads();

  for (int kb = 0; kb < KSTEPS; ++kb) {
    const int cur = kb & 1;
    if (kb + 1 < KSTEPS) STAGE(cur ^ 1, kb + 1)
    f16x8 af[4], bf[4];
#pragma unroll
    for (int m = 0; m < 4; ++m) {
      const int row = wr * 64 + m * 16 + lr;
      af[m] = *(const f16x8*)(As[cur] + row * 32 + ((lk ^ (row & 3)) * 8));
    }
#pragma unroll
    for (int n = 0; n < 4; ++n) {
      const int row = wc * 64 + n * 16 + lr;
      bf[n] = *(const f16x8*)(Bs[cur] + row * 32 + ((lk ^ (row & 3)) * 8));
    }
#pragma unroll
    for (int m = 0; m < 4; ++m)
#pragma unroll
      for (int n = 0; n < 4; ++n)
        acc[m][n] = __builtin_amdgcn_mfma_f32_16x16x32_f16(af[m], bf[n],
                                                           acc[m][n], 0, 0, 0);
    __syncthreads();  // drains vmcnt (stage of kb+1 complete) + lgkm
  }
#undef STAGE

#pragma unroll
  for (int m = 0; m < 4; ++m) {
    const int rowb = i_base + wr * 64 + m * 16 + lk * 4;
#pragma unroll
    for (int n = 0; n < 4; ++n) {
      const int col = bn * 128 + wc * 64 + n * 16 + lr;
      if (EP == 0) {
        if (col < 384) {
          const float bv = bias[col];
#pragma unroll
          for (int j = 0; j < 4; ++j)
            out0[(size_t)(rowb + j) * 384 + col] = acc[m][n][j] + bv;
        } else {
          const int c2 = col - 384;
#pragma unroll
          for (int j = 0; j < 4; ++j)
            out1[(size_t)(rowb + j) * 2048 + c2] = __float2half(acc[m][n][j]);
        }
      } else {
        const float bv = bias[col];
        float4 v;
        v.x = acc[m][n][0] + bv; v.y = acc[m][n][1] + bv;
        v.z = acc[m][n][2] + bv; v.w = acc[m][n][3] + bv;
        *(float4*)(out0 + ((size_t)(rowb >> 8) * 256 + col) * 256 + (rowb & 255)) = v;
      }
    }
  }
}

// ---------------- K2: wave-cooperative sampling, LDS-staged coalesced stores ----------------
__global__ __launch_bounds__(256) void k2_sample(
    const float* __restrict__ refp,
    const float* __restrict__ inp,
    const float* __restrict__ offs,
    __half* __restrict__ kv) {
  __shared__ float swx0[256], swx1[256];
  __shared__ float szy00[256], szy01[256], szy10[256], szy11[256];
  __shared__ int   spx0[256], spx1[256];
  __shared__ int   spzy00[256], spzy01[256], spzy10[256], spzy11[256];
  __shared__ __half res[256][34];

  const int bid = blockIdx.x;
  const int pp = bid & 3;
  const int a  = (bid >> 2) & 31;
  const int l  = (bid >> 7) & 3;
  const int h  = (bid >> 9) & 7;
  const int b  = bid >> 12;
  const int tid = threadIdx.x;

  const int S_[4]  = {48, 24, 12, 6};
  const int ST_[4] = {0, 110592, 124416, 126144};
  const int Sl = S_[l];
  const int st = ST_[l];
  const float Sf = (float)Sl;

  {  // phase 1: geometry for sample s = tid
    const int p = tid & 3, t = tid >> 2;
    const int q = a * 256 + pp * 64 + t;
    const float* rp = refp + ((size_t)(b * LQ + q) * 4 + l) * 3;
    const float r0 = rp[0], r1 = rp[1], r2 = rp[2];
    const float* op = offs + (size_t)(b * LQ + q) * 384 + (h * 48 + l * 12 + p * 3);
    const float o0 = op[0], o1 = op[1], o2 = op[2];

    const float g0 = fmaxf(2.f * (r0 + o0 / Sf) - 1.f, 0.f);
    const float g1 = fmaxf(2.f * (r1 + o1 / Sf) - 1.f, 0.f);
    const float g2 = fmaxf(2.f * (r2 + o2 / Sf) - 1.f, 0.f);

    const float ix = ((g0 + 1.f) * Sf - 1.f) * 0.5f;   // -> W (x)
    const float iy = ((g1 + 1.f) * Sf - 1.f) * 0.5f;   // -> H (y)
    const float iz = ((g2 + 1.f) * Sf - 1.f) * 0.5f;   // -> D (z)

    const float x0f = floorf(ix), y0f = floorf(iy), z0f = floorf(iz);
    const float fx = ix - x0f, fy = iy - y0f, fz = iz - z0f;
    const int x0 = (int)x0f, y0 = (int)y0f, z0 = (int)z0f;
    const float wx0 = (x0 < Sl) ? 1.f - fx : 0.f;
    const float wx1 = (x0 + 1 < Sl) ? fx : 0.f;
    const float wy0 = (y0 < Sl) ? 1.f - fy : 0.f;
    const float wy1 = (y0 + 1 < Sl) ? fy : 0.f;
    const float wz0 = (z0 < Sl) ? 1.f - fz : 0.f;
    const float wz1 = (z0 + 1 < Sl) ? fz : 0.f;
    const int px0 = min(x0, Sl - 1);
    const int px1 = min(x0 + 1, Sl - 1);
    const int py0 = min(y0, Sl - 1) * Sl;
    const int py1 = min(y0 + 1, Sl - 1) * Sl;
    const int pz0 = min(z0, Sl - 1) * Sl * Sl;
    const int pz1 = min(z0 + 1, Sl - 1) * Sl * Sl;
    swx0[tid] = wx0;            swx1[tid] = wx1;
    szy00[tid] = wz0 * wy0;     szy01[tid] = wz0 * wy1;
    szy10[tid] = wz1 * wy0;     szy11[tid] = wz1 * wy1;
    spx0[tid] = px0;            spx1[tid] = px1;
    spzy00[tid] = pz0 + py0;    spzy01[tid] = pz0 + py1;
    spzy10[tid] = pz1 + py0;    spzy11[tid] = pz1 + py1;
  }
  __syncthreads();

  const int c4 = tid & 7, s8 = tid >> 3;
  const float* base = inp + ((size_t)b * LEN_IN_ + st) * 256 + h * 32 + c4 * 4;

#pragma unroll
  for (int u = 0; u < 8; ++u) {
    const int s = u * 32 + s8;
    const float wx0 = swx0[s], wx1 = swx1[s];
    const float w00 = szy00[s], w01 = szy01[s];
    const float w10 = szy10[s], w11 = szy11[s];
    const int px0 = spx0[s], px1 = spx1[s];
    const int pzy00 = spzy00[s], pzy01 = spzy01[s];
    const int pzy10 = spzy10[s], pzy11 = spzy11[s];

    float ax = 0.f, ay = 0.f, az = 0.f, aw = 0.f;
#define CORNER(PZY, PX, WGT)                                             \
    {                                                                    \
      const float4 v = *(const float4*)(base + (size_t)((PZY) + (PX)) * 256); \
      const float wg = (WGT);                                            \
      ax += wg * v.x; ay += wg * v.y; az += wg * v.z; aw += wg * v.w;    \
    }
    CORNER(pzy00, px0, w00 * wx0)
    CORNER(pzy00, px1, w00 * wx1)
    CORNER(pzy01, px0, w01 * wx0)
    CORNER(pzy01, px1, w01 * wx1)
    CORNER(pzy10, px0, w10 * wx0)
    CORNER(pzy10, px1, w10 * wx1)
    CORNER(pzy11, px0, w11 * wx0)
    CORNER(pzy11, px1, w11 * wx1)
#undef CORNER
    f16x4 r4 = {(f16)ax, (f16)ay, (f16)az, (f16)aw};
    *(f16x4*)&res[s][c4 * 4] = r4;
  }
  __syncthreads();

  // phase 3: coalesced stores; tid == kv column j
  const size_t base0 = ((size_t)(b * LQ + h * 1024 + a) * 16 + (l * 4 + pp)) * 256 + tid;
#pragma unroll
  for (int c = 0; c < 32; ++c)
    kv[base0 + (size_t)c * 131072] = res[tid][c];
}

// ---------------- K3: wave-per-row logits/softmax/weighted-sum ----------------
__global__ __launch_bounds__(256) void k3_mid(
    const __half* __restrict__ t16h,
    const __half* __restrict__ kvh,
    __half* __restrict__ Sh) {
  __shared__ float attn_s[4][128];
  const int tid = threadIdx.x;
  const int wv = tid >> 6, L = tid & 63;
  const int i = blockIdx.x * 4 + wv;
  const int q = i & 8191, b = i >> 13;
  const int k = L & 15, ds = L >> 4;
  const f16* tp = (const f16*)t16h + (size_t)i * 2048;
  const f16* kp = (const f16*)kvh + (size_t)i * 4096;

  float lg[8] = {0.f, 0.f, 0.f, 0.f, 0.f, 0.f, 0.f, 0.f};
#pragma unroll
  for (int c = 0; c < 8; ++c) {
    const int d0 = ds * 64 + c * 8;
    const f16x8 kvv = *(const f16x8*)(kp + k * 256 + d0);
#pragma unroll
    for (int h = 0; h < 8; ++h) {
      const f16x8 tv = *(const f16x8*)(tp + h * 256 + d0);
#pragma unroll
      for (int j2 = 0; j2 < 4; ++j2) {
        f16x2 a2 = {kvv[j2 * 2], kvv[j2 * 2 + 1]};
        f16x2 b2 = {tv[j2 * 2], tv[j2 * 2 + 1]};
        lg[h] = __builtin_amdgcn_fdot2(a2, b2, lg[h], false);
      }
    }
  }
#pragma unroll
  for (int h = 0; h < 8; ++h) {
    lg[h] += __shfl_xor(lg[h], 16);
    lg[h] += __shfl_xor(lg[h], 32);
    lg[h] *= 0.17677669529663689f;
  }
  float at[8];
#pragma unroll
  for (int h = 0; h < 8; ++h) {
    float m = lg[h];
#pragma unroll
    for (int off = 8; off >= 1; off >>= 1) m = fmaxf(m, __shfl_xor(m, off));
    const float e = __expf(lg[h] - m);
    float s = e;
#pragma unroll
    for (int off = 8; off >= 1; off >>= 1) s += __shfl_xor(s, off);
    at[h] = e / s;
  }
  if (ds == 0) {
#pragma unroll
    for (int h = 0; h < 8; ++h) attn_s[wv][h * 16 + k] = at[h];
  }
  __syncthreads();

  float sacc[32];
#pragma unroll
  for (int x = 0; x < 32; ++x) sacc[x] = 0.f;
#pragma unroll
  for (int k4 = 0; k4 < 4; ++k4) {
    f16x4 kvd[4];
#pragma unroll
    for (int j = 0; j < 4; ++j)
      kvd[j] = *(const f16x4*)(kp + (k4 * 4 + j) * 256 + L * 4);
#pragma unroll
    for (int h = 0; h < 8; ++h) {
      const float4 a4 = *(const float4*)&attn_s[wv][h * 16 + k4 * 4];
      const float av[4] = {a4.x, a4.y, a4.z, a4.w};
#pragma unroll
      for (int j = 0; j < 4; ++j)
#pragma unroll
        for (int dd = 0; dd < 4; ++dd)
          sacc[h * 4 + dd] += av[j] * (float)kvd[j][dd];
    }
  }
  const size_t rho = (size_t)b * 8192 + (size_t)(q & 31) * 256 + (q >> 5);
  f16* Sp = (f16*)Sh + rho * 2048 + L * 4;
#pragma unroll
  for (int h = 0; h < 8; ++h) {
    f16x4 sv = {(f16)sacc[h * 4 + 0], (f16)sacc[h * 4 + 1],
                (f16)sacc[h * 4 + 2], (f16)sacc[h * 4 + 3]};
    *(f16x4*)(Sp + h * 256) = sv;
  }
}

extern "C" void kernel_launch(void* const* d_in, const int* in_sizes, int n_in,
                              void* d_out, int out_size, void* d_ws, size_t ws_size,
                              hipStream_t stream) {
  const float* query = (const float*)d_in[0];
  const float* refp  = (const float*)d_in[1];
  const float* inp   = (const float*)d_in[2];
  const float* woff  = (const float*)d_in[3];
  const float* boff  = (const float*)d_in[4];
  const float* wqkv  = (const float*)d_in[5];
  const float* wo    = (const float*)d_in[7];
  const float* bo    = (const float*)d_in[8];
  float* out = (float*)d_out;

  char* ws = (char*)d_ws;
  f16*    q16  = (f16*)(ws + 0);                    // 16384*256*2      = 8.4 MB
  f16*    Bw   = (f16*)(ws + 8388608);              // 2432*256*2       = 1.25 MB
  float*  offs = (float*)(ws + 9633792);            // 16384*384*4      = 25.2 MB
  __half* S    = (__half*)(ws + 9633792);           // alias offs (dead after K2); 67.1 MB
  __half* t16  = (__half*)(ws + 76742656);          // 16384*2048*2     = 67.1 MB
  __half* kv   = (__half*)(ws + 143851520);         // 16384*16*256*2   = 134.2 MB
  f16*    Mw   = (f16*)(ws + 278069248);            // 256*2048*2       = 1.05 MB

  k0_prep<<<8576, 256, 0, stream>>>(query, q16, woff, wqkv, Bw, wo, Mw);
  // K1: offs(384 cols f32) + t(2048 cols fp16) = 16384 x 2432, K=256
  gemm128<8, 0><<<128 * 19, 256, 0, stream>>>(q16, 256, Bw, 256, 19, boff, offs, t16);
  k2_sample<<<8192, 256, 0, stream>>>(refp, inp, offs, kv);
  k3_mid<<<4096, 256, 0, stream>>>(t16, kv, S);
  // K4: out = S @ Mw^T + bO  (16384 x 256, K=2048), scrambled store
  gemm128<64, 1><<<128 * 2, 256, 0, stream>>>((const f16*)S, 2048, Mw, 2048, 2, bo, out, nullptr);
}